// Round 1
// 224.333 us; speedup vs baseline: 1.1286x; 1.1286x over previous
//
#include <hip/hip_runtime.h>
#include <hip/hip_bf16.h>
#include <math.h>

// ---------------- types ----------------
typedef short s16x8 __attribute__((ext_vector_type(8)));
typedef float f32x4 __attribute__((ext_vector_type(4)));

// ---------------- fp32 <-> bf16 ----------------
__device__ inline unsigned short f2bf(float x) {
    unsigned int u = __float_as_uint(x);
    unsigned int r = (u + 0x7fffu + ((u >> 16) & 1u)) >> 16;
    return (unsigned short)r;
}
__device__ inline float bf2f(unsigned short u) {
    return __uint_as_float(((unsigned int)u) << 16);
}

// fast tanh: 1 - 2/(exp(2x)+1); saturates correctly at +-inf
__device__ inline float fast_tanh(float x) {
    float e = __expf(2.0f * x);
    return 1.0f - 2.0f * __builtin_amdgcn_rcpf(e + 1.0f);
}

// ---------------- fused: cvt x, cvt W_ih, pack W_lin -> bf16 [16][2336] ------
__global__ void cvtprep_kernel(const float* __restrict__ x,
                               const float* __restrict__ W_ih,
                               const float* __restrict__ W_lin,
                               unsigned short* __restrict__ xb,
                               unsigned short* __restrict__ wb,
                               unsigned short* __restrict__ wlb) {
    int blk = blockIdx.x;
    int tid = threadIdx.x;
    if (blk < 16384) {
        int i = blk * 256 + tid;
        float4 v = ((const float4*)x)[i];
        ushort4 o; o.x = f2bf(v.x); o.y = f2bf(v.y); o.z = f2bf(v.z); o.w = f2bf(v.w);
        ((ushort4*)xb)[i] = o;
    } else if (blk < 20480) {
        int i = (blk - 16384) * 256 + tid;
        float4 v = ((const float4*)W_ih)[i];
        ushort4 o; o.x = f2bf(v.x); o.y = f2bf(v.y); o.z = f2bf(v.z); o.w = f2bf(v.w);
        ((ushort4*)wb)[i] = o;
    } else {
        int idx = (blk - 20480) * 256 + tid;   // 16*2336 = 37376
        if (idx < 37376) {
            int c = idx / 2336, k = idx - c * 2336;
            float v = (c < 10 && k < 2318) ? W_lin[c * 2318 + k] : 0.f;
            wlb[idx] = f2bf(v);
        }
    }
}

// ---------------- GEMM: Hb = bf16(tanh(x @ W_ih^T + b)) ----------------
// 256x256 tile, BK=64, 512 thr (2x4 waves, 128x64 C each), 8-phase schedule
// (T2 swizzle + T3/T4 counted vmcnt + T5 setprio). LDS 128 KiB: 2 bufs x
// (A[2 halves][128][64] + B[2 halves][128][64]) bf16.
// Swizzle: 16B slot s of row r holds k-group (s ^ (r&7)); applied on the
// GLOBAL source so global_load_lds dest stays linear; ds_read applies the
// same XOR -> 2-way bank aliasing only (free).
// Staging units = 8 KB (64 rows, 1 load/thread). Per tile t (4 phases):
//   p1: read B(all)+A q0 | stage t+1 A rows64-127 (other buf; region was
//       consumed during tiles t-1 p3/p4)
//   p2: read A q1        | stage t+2 B-top   (this buf; B consumed in p1)
//   p3: read A q2        | stage t+2 B-bottom
//   p4: read A q3        | stage t+2 A rows0-63 (consumed in p1/p2); vmcnt(6)
// Boundary invariant: vmcnt(6) leaves only t+2's 6 units in flight -> tile
// t+1 fully resident before its phase-1 reads. Epilogue drains vmcnt(0) once.

#define MFMA_(a, b, c) __builtin_amdgcn_mfma_f32_16x16x32_bf16(a, b, c, 0, 0, 0)

__device__ inline s16x8 frag_ld(const unsigned short* hbase, int row, int ksub, int quad) {
    int slot = (ksub * 4 + quad) ^ (row & 7);
    return *(const s16x8*)(hbase + row * 64 + slot * 8);
}

// stage one 8KB unit: 64 rows x 64 cols bf16, 1x16B load per thread
__device__ inline void stage_u(const unsigned short* __restrict__ gmat, int half,
                               int rowoff, int kt, unsigned short* lmat, int tid) {
    int r = tid >> 3, s = tid & 7;
    int lr = rowoff + r;
    int ks = (s ^ (lr & 7)) << 3;
    const unsigned short* gp = gmat + (size_t)(half * 128 + lr) * 2048 + kt * 64 + ks;
    __builtin_amdgcn_global_load_lds(
        (const __attribute__((address_space(1))) void*)gp,
        (__attribute__((address_space(3))) void*)(lmat + half * 8192 + lr * 64 + s * 8),
        16, 0, 0);
}

#define LOAD_AQ(q)                                                       \
    af0 = frag_ld(Ah, (q) * 32 +      mrow, 0, quad);                    \
    af1 = frag_ld(Ah, (q) * 32 + 16 + mrow, 0, quad);                    \
    af2 = frag_ld(Ah, (q) * 32 +      mrow, 1, quad);                    \
    af3 = frag_ld(Ah, (q) * 32 + 16 + mrow, 1, quad);

#define MFMA_Q(q)                                                        \
    acc[(q)*2 + 0][0] = MFMA_(af0, bf00, acc[(q)*2 + 0][0]);             \
    acc[(q)*2 + 0][1] = MFMA_(af0, bf01, acc[(q)*2 + 0][1]);             \
    acc[(q)*2 + 0][2] = MFMA_(af0, bf02, acc[(q)*2 + 0][2]);             \
    acc[(q)*2 + 0][3] = MFMA_(af0, bf03, acc[(q)*2 + 0][3]);             \
    acc[(q)*2 + 1][0] = MFMA_(af1, bf00, acc[(q)*2 + 1][0]);             \
    acc[(q)*2 + 1][1] = MFMA_(af1, bf01, acc[(q)*2 + 1][1]);             \
    acc[(q)*2 + 1][2] = MFMA_(af1, bf02, acc[(q)*2 + 1][2]);             \
    acc[(q)*2 + 1][3] = MFMA_(af1, bf03, acc[(q)*2 + 1][3]);             \
    acc[(q)*2 + 0][0] = MFMA_(af2, bf10, acc[(q)*2 + 0][0]);             \
    acc[(q)*2 + 0][1] = MFMA_(af2, bf11, acc[(q)*2 + 0][1]);             \
    acc[(q)*2 + 0][2] = MFMA_(af2, bf12, acc[(q)*2 + 0][2]);             \
    acc[(q)*2 + 0][3] = MFMA_(af2, bf13, acc[(q)*2 + 0][3]);             \
    acc[(q)*2 + 1][0] = MFMA_(af3, bf10, acc[(q)*2 + 1][0]);             \
    acc[(q)*2 + 1][1] = MFMA_(af3, bf11, acc[(q)*2 + 1][1]);             \
    acc[(q)*2 + 1][2] = MFMA_(af3, bf12, acc[(q)*2 + 1][2]);             \
    acc[(q)*2 + 1][3] = MFMA_(af3, bf13, acc[(q)*2 + 1][3]);

#define PHASE_CORE(q)                                                    \
    __builtin_amdgcn_s_barrier();                                        \
    asm volatile("s_waitcnt lgkmcnt(0)" ::: "memory");                   \
    __builtin_amdgcn_s_setprio(1);                                       \
    MFMA_Q(q);                                                           \
    __builtin_amdgcn_s_setprio(0);

__global__ __launch_bounds__(512) void gemm_tanh_kernel(
    const unsigned short* __restrict__ A, const unsigned short* __restrict__ Bm,
    const float* __restrict__ b_ih, const float* __restrict__ b_hh,
    unsigned short* __restrict__ Hb)
{
    __shared__ __align__(16) unsigned short lds[2][2][16384];  // [buf][A/B][half*128*64]

    const int tid  = threadIdx.x;
    const int lane = tid & 63;
    const int wave = tid >> 6;
    const int wgid = blockIdx.x;
    const int cblk = wgid & 7;    // column chunk per XCD: all 32 blocks of a
    const int rblk = wgid >> 3;   // column land on one XCD -> B panel L2-hot
    const int row0 = rblk * 256;
    const int col0 = cblk * 256;
    const int wm   = wave >> 2;   // 0..1 : A half / 128-row block
    const int wn   = wave & 3;    // 0..3 : 64-col block
    const int quad = lane >> 4;
    const int mrow = lane & 15;
    const int NT   = 32;          // K tiles of 64

    const unsigned short* Ag = A  + (size_t)row0 * 2048;
    const unsigned short* Bg = Bm + (size_t)col0 * 2048;

    f32x4 acc[8][4];
#pragma unroll
    for (int i = 0; i < 8; ++i)
#pragma unroll
        for (int j = 0; j < 4; ++j) acc[i][j] = f32x4{0.f, 0.f, 0.f, 0.f};

    // prologue: tile0 fully (8 units), then tile1's 6 early units
    stage_u(Ag, 0, 0,  0, lds[0][0], tid);  stage_u(Ag, 0, 64, 0, lds[0][0], tid);
    stage_u(Ag, 1, 0,  0, lds[0][0], tid);  stage_u(Ag, 1, 64, 0, lds[0][0], tid);
    stage_u(Bg, 0, 0,  0, lds[0][1], tid);  stage_u(Bg, 0, 64, 0, lds[0][1], tid);
    stage_u(Bg, 1, 0,  0, lds[0][1], tid);  stage_u(Bg, 1, 64, 0, lds[0][1], tid);
    stage_u(Bg, 0, 0,  1, lds[1][1], tid);  stage_u(Bg, 0, 64, 1, lds[1][1], tid);
    stage_u(Bg, 1, 0,  1, lds[1][1], tid);  stage_u(Bg, 1, 64, 1, lds[1][1], tid);
    stage_u(Ag, 0, 0,  1, lds[1][0], tid);  stage_u(Ag, 1, 0,  1, lds[1][0], tid);
    asm volatile("s_waitcnt vmcnt(6)" ::: "memory");  // tile0 resident
    __builtin_amdgcn_s_barrier();

    for (int t = 0; t < NT; ++t) {
        const int buf = t & 1;
        unsigned short* LA  = lds[buf][0];
        unsigned short* LB  = lds[buf][1];
        unsigned short* NLA = lds[buf ^ 1][0];
        const unsigned short* Ah = LA + wm * 8192;
        const unsigned short* Bh = LB + (wn >> 1) * 8192;
        const int bco = (wn & 1) * 64;

        s16x8 bf00, bf01, bf02, bf03, bf10, bf11, bf12, bf13;
        s16x8 af0, af1, af2, af3;

        // ===== phase 1: B full + A q0 | stage t+1 A rows 64..127 =====
        bf00 = frag_ld(Bh, bco +  0 + mrow, 0, quad);
        bf01 = frag_ld(Bh, bco + 16 + mrow, 0, quad);
        bf02 = frag_ld(Bh, bco + 32 + mrow, 0, quad);
        bf03 = frag_ld(Bh, bco + 48 + mrow, 0, quad);
        bf10 = frag_ld(Bh, bco +  0 + mrow, 1, quad);
        bf11 = frag_ld(Bh, bco + 16 + mrow, 1, quad);
        bf12 = frag_ld(Bh, bco + 32 + mrow, 1, quad);
        bf13 = frag_ld(Bh, bco + 48 + mrow, 1, quad);
        LOAD_AQ(0);
        if (t + 1 < NT) {
            stage_u(Ag, 0, 64, t + 1, NLA, tid);
            stage_u(Ag, 1, 64, t + 1, NLA, tid);
        }
        asm volatile("s_waitcnt lgkmcnt(8)" ::: "memory");  // 12 ds_reads in flight
        PHASE_CORE(0);
        __builtin_amdgcn_s_barrier();

        // ===== phase 2: A q1 | stage t+2 B-top =====
        LOAD_AQ(1);
        if (t + 2 < NT) {
            stage_u(Bg, 0, 0,  t + 2, LB, tid);
            stage_u(Bg, 0, 64, t + 2, LB, tid);
        }
        PHASE_CORE(1);
        __builtin_amdgcn_s_barrier();

        // ===== phase 3: A q2 | stage t+2 B-bottom =====
        LOAD_AQ(2);
        if (t + 2 < NT) {
            stage_u(Bg, 1, 0,  t + 2, LB, tid);
            stage_u(Bg, 1, 64, t + 2, LB, tid);
        }
        PHASE_CORE(2);
        __builtin_amdgcn_s_barrier();

        // ===== phase 4: A q3 | stage t+2 A rows 0..63; boundary vmcnt =====
        LOAD_AQ(3);
        if (t + 2 < NT) {
            stage_u(Ag, 0, 0, t + 2, LA, tid);
            stage_u(Ag, 1, 0, t + 2, LA, tid);
        }
        PHASE_CORE(3);
        if (t + 2 < NT) {
            asm volatile("s_waitcnt vmcnt(6)" ::: "memory");   // t+1 resident
        } else if (t + 1 < NT) {
            asm volatile("s_waitcnt vmcnt(0)" ::: "memory");   // final drain
        }
        __builtin_amdgcn_s_barrier();
    }

    float bias[4];
#pragma unroll
    for (int j = 0; j < 4; ++j) {
        int gc = col0 + wn * 64 + j * 16 + mrow;
        bias[j] = b_ih[gc] + b_hh[gc];
    }
#pragma unroll
    for (int i = 0; i < 8; ++i) {
#pragma unroll
        for (int rr = 0; rr < 4; ++rr) {
            int grow = row0 + wm * 128 + i * 16 + quad * 4 + rr;
#pragma unroll
            for (int j = 0; j < 4; ++j) {
                int gc = col0 + wn * 64 + j * 16 + mrow;
                float v = acc[i][j][rr] + bias[j];
                Hb[(size_t)grow * 2048 + gc] = f2bf(fast_tanh(v));
            }
        }
    }
}

// ---------------- AvgPool1d(k=45,s=45): 8 rows/block, coalesced f-major out --
__global__ __launch_bounds__(256) void pool_kernel(
    const unsigned short* __restrict__ Hb, float* __restrict__ pooled_t) {
    __shared__ unsigned short hs[8 * 2048];  // 32 KB
    __shared__ float outs[45 * 8];
    int b0 = blockIdx.x * 8;
    int tid = threadIdx.x;
    const ushort4* src = (const ushort4*)(Hb + (size_t)b0 * 2048);
    ushort4* dst = (ushort4*)hs;
    for (int i = tid; i < 4096; i += 256) dst[i] = src[i];
    __syncthreads();
    for (int o = tid; o < 360; o += 256) {
        int f = o % 45, r = o / 45;
        const unsigned short* row = hs + r * 2048 + f * 45;
        float s = 0.f;
#pragma unroll
        for (int k = 0; k < 45; ++k) s += bf2f(row[k]);
        outs[f * 8 + r] = s * (1.0f / 45.0f);
    }
    __syncthreads();
    for (int o = tid; o < 360; o += 256) {
        int f = o >> 3, r = o & 7;
        pooled_t[f * 8192 + b0 + r] = outs[o];
    }
}

// ---------------- per-feature dual prefix sum (sum, sum^2), single pass ------
__global__ __launch_bounds__(256) void scan_kernel(
    const float* __restrict__ pooled_t,
    float* __restrict__ cs_t, float* __restrict__ cs2_t) {
    __shared__ float t1[256], t2[256];
    int f = blockIdx.x;
    int tid = threadIdx.x;
    const float* p = pooled_t + f * 8192;
    int base = tid * 32;
    float loc[32];
    float s1 = 0.f, s2 = 0.f;
#pragma unroll
    for (int i = 0; i < 32; ++i) {
        float v = p[base + i];
        loc[i] = v; s1 += v; s2 += v * v;
    }
    t1[tid] = s1; t2[tid] = s2;
    __syncthreads();
    for (int d = 1; d < 256; d <<= 1) {
        float a1 = (tid >= d) ? t1[tid - d] : 0.f;
        float a2 = (tid >= d) ? t2[tid - d] : 0.f;
        __syncthreads();
        t1[tid] += a1; t2[tid] += a2;
        __syncthreads();
    }
    float r1 = t1[tid] - s1, r2 = t2[tid] - s2;  // exclusive offsets
    float* c1 = cs_t + f * 8192;
    float* c2 = cs2_t + f * 8192;
#pragma unroll
    for (int i = 0; i < 32; ++i) {
        float v = loc[i];
        r1 += v; r2 += v * v;
        c1[base + i] = r1; c2[base + i] = r2;
    }
}

// ---------------- final: MFMA GEMM [Hb|est](8192x2336) @ Wb^T(16x2336) -------
#define ESTRIDE 290
__global__ __launch_bounds__(256) void final_kernel(
    const unsigned short* __restrict__ Hb,
    const float* __restrict__ cs_t, const float* __restrict__ cs2_t,
    const unsigned short* __restrict__ Wb, const float* __restrict__ b_lin,
    float* __restrict__ out) {
    __shared__ unsigned short Es[32 * ESTRIDE];  // 18.1 KB
    __shared__ float comb[2 * 16 * 17];          // 2.1 KB
    int tid = threadIdx.x;
    int lane = tid & 63;
    int wave = tid >> 6;
    int b0 = blockIdx.x * 32;

    // build est tile: (f,j,r) -> mean/var from prefix sums (all L2-hot)
    for (int i = tid; i < 135 * 32; i += 256) {
        int fj = i >> 5, r = i & 31;
        int f = fj / 3, j = fj - 3 * f;
        int b = b0 + r;
        int L = (j == 0) ? 32 : (j == 1) ? 128 : 512;
        const float* c1 = cs_t + f * 8192;
        const float* c2 = cs2_t + f * 8192;
        float a1 = c1[b], a2 = c2[b];
        float p1 = 0.f, p2 = 0.f;
        if (b >= L) { p1 = c1[b - L]; p2 = c2[b - L]; }
        float cnt = (float)((b + 1 < L) ? (b + 1) : L);
        float m = (a1 - p1) / cnt;
        float v = (a2 - p2) / cnt - m * m;
        int d0 = f * 6 + j * 2;
        Es[r * ESTRIDE + d0]     = f2bf(m);
        Es[r * ESTRIDE + d0 + 1] = f2bf(v);
    }
    // zero pad d in [270, 288)
    for (int i = tid; i < 32 * 18; i += 256) {
        int r = i / 18, d = 270 + i % 18;
        Es[r * ESTRIDE + d] = 0;
    }
    __syncthreads();

    const int t = wave >> 1;
    const int kh = wave & 1;
    const int quad = lane >> 4;
    const int mrow = lane & 15;
    const int rowt = b0 + t * 16;

    f32x4 acc = f32x4{0.f, 0.f, 0.f, 0.f};
    const unsigned short* arow = Hb + (size_t)(rowt + mrow) * 2048 + kh * 1024 + quad * 8;
    const unsigned short* brow = Wb + (size_t)mrow * 2336 + kh * 1024 + quad * 8;
#pragma unroll 4
    for (int k = 0; k < 1024; k += 32) {
        s16x8 a = *(const s16x8*)(arow + k);
        s16x8 b = *(const s16x8*)(brow + k);
        acc = __builtin_amdgcn_mfma_f32_16x16x32_bf16(a, b, acc, 0, 0, 0);
    }
    if (kh) {
        const unsigned short* erow = Es + (t * 16 + mrow) * ESTRIDE + quad * 8;
        const unsigned short* wrow = Wb + (size_t)mrow * 2336 + 2048 + quad * 8;
#pragma unroll
        for (int k = 0; k < 288; k += 32) {
            s16x8 a = *(const s16x8*)(erow + k);
            s16x8 b = *(const s16x8*)(wrow + k);
            acc = __builtin_amdgcn_mfma_f32_16x16x32_bf16(a, b, acc, 0, 0, 0);
        }
    }

    float* cb = comb + t * 272;
    if (kh == 0) {
#pragma unroll
        for (int r = 0; r < 4; ++r) cb[(quad * 4 + r) * 17 + mrow] = acc[r];
    }
    __syncthreads();
    if (kh == 1) {
#pragma unroll
        for (int r = 0; r < 4; ++r) cb[(quad * 4 + r) * 17 + mrow] += acc[r];
    }
    __syncthreads();

    if (tid < 32) {
        const float* base = comb + (tid >> 4) * 272 + (tid & 15) * 17;
        float lg[10];
        float mx = -1e30f;
#pragma unroll
        for (int c = 0; c < 10; ++c) {
            lg[c] = base[c] + b_lin[c];
            mx = fmaxf(mx, lg[c]);
        }
        float s = 0.f;
#pragma unroll
        for (int c = 0; c < 10; ++c) { lg[c] = expf(lg[c] - mx); s += lg[c]; }
        float inv = 1.0f / s;
#pragma unroll
        for (int c = 0; c < 10; ++c) out[(size_t)(b0 + tid) * 10 + c] = lg[c] * inv;
    }
}

// ---------------- launch ----------------
extern "C" void kernel_launch(void* const* d_in, const int* in_sizes, int n_in,
                              void* d_out, int out_size, void* d_ws, size_t ws_size,
                              hipStream_t stream) {
    const float* x     = (const float*)d_in[0];   // (8192,1,2048)
    const float* W_ih  = (const float*)d_in[1];   // (2048,2048)
    // d_in[2] = W_hh unused: h0 == 0 so the recurrent term vanishes
    const float* b_ih  = (const float*)d_in[3];
    const float* b_hh  = (const float*)d_in[4];
    const float* W_lin = (const float*)d_in[5];   // (10, 2318)
    const float* b_lin = (const float*)d_in[6];
    float* out = (float*)d_out;

    char* ws = (char*)d_ws;
    unsigned short* xb  = (unsigned short*)(ws);                 // 33554432 B
    unsigned short* wb  = (unsigned short*)(ws + 33554432);      //  8388608 B
    unsigned short* Hb  = (unsigned short*)(ws + 41943040);      // 33554432 B
    float* pooled_t     = (float*)(ws + 75497472);               //  1474560 B
    float* cs_t         = (float*)(ws + 76972032);               //  1474560 B
    float* cs2_t        = (float*)(ws + 78446592);               //  1474560 B
    unsigned short* wlb = (unsigned short*)(ws + 79921152);      //    74752 B (~80 MB)

    cvtprep_kernel<<<20626, 256, 0, stream>>>(x, W_ih, W_lin, xb, wb, wlb);
    gemm_tanh_kernel<<<256, 512, 0, stream>>>(xb, wb, b_ih, b_hh, Hb);
    pool_kernel<<<1024, 256, 0, stream>>>(Hb, pooled_t);
    scan_kernel<<<45, 256, 0, stream>>>(pooled_t, cs_t, cs2_t);
    final_kernel<<<256, 256, 0, stream>>>(Hb, cs_t, cs2_t, wlb, b_lin, out);
}